// Round 2
// baseline (325.489 us; speedup 1.0000x reference)
//
#include <hip/hip_runtime.h>
#include <stdint.h>

#define B_N 16
#define C_N 512
#define S_N 1024
#define G_N 32
#define NH  8
#define HD  64

typedef __attribute__((ext_vector_type(8))) short bf16x8;
typedef __attribute__((ext_vector_type(4))) float f32x4;
typedef unsigned short u16;
typedef unsigned int   u32;
typedef __attribute__((ext_vector_type(4))) u16 u16x4;

__device__ __forceinline__ u16 f2bf(float f) {
  u32 u = __builtin_bit_cast(u32, f);
  u32 r = (u + 0x7fffu + ((u >> 16) & 1u)) >> 16;   // RNE
  return (u16)r;
}

__device__ __forceinline__ void gll16(const void* g, void* l) {
  __builtin_amdgcn_global_load_lds((const __attribute__((address_space(1))) u32*)g,
                                   (__attribute__((address_space(3))) u32*)l, 16, 0, 0);
}

// ---------------- GroupNorm stats: one block per (b,g) ----------------
__global__ __launch_bounds__(256) void gn_stats(const float* __restrict__ x,
                                                float* __restrict__ stats) {
  const int bg = blockIdx.x;                    // b*32+g
  const float4* xv = (const float4*)(x + (size_t)bg * (16 * S_N));
  float s = 0.f, ss = 0.f;
  for (int i = threadIdx.x; i < 4096; i += 256) {
    float4 v = xv[i];
    s  += v.x + v.y + v.z + v.w;
    ss += v.x*v.x + v.y*v.y + v.z*v.z + v.w*v.w;
  }
  #pragma unroll
  for (int m = 1; m < 64; m <<= 1) { s += __shfl_xor(s, m); ss += __shfl_xor(ss, m); }
  __shared__ float red[2][4];
  const int wid = threadIdx.x >> 6;
  if ((threadIdx.x & 63) == 0) { red[0][wid] = s; red[1][wid] = ss; }
  __syncthreads();
  if (threadIdx.x == 0) {
    float S1 = red[0][0]+red[0][1]+red[0][2]+red[0][3];
    float S2 = red[1][0]+red[1][1]+red[1][2]+red[1][3];
    float mean = S1 * (1.f/16384.f);
    float var  = S2 * (1.f/16384.f) - mean*mean;
    stats[bg*2]   = mean;
    stats[bg*2+1] = rsqrtf(var + 1e-5f);
  }
}

// ------------- normalize + transpose -> h_t[b][s][c] (bf16) -------------
__global__ __launch_bounds__(256) void gn_apply_t(const float* __restrict__ x,
                                                  const float* __restrict__ stats,
                                                  const float* __restrict__ nw,
                                                  const float* __restrict__ nb,
                                                  u16* __restrict__ h_t) {
  const int c0 = blockIdx.x * 32, s0 = blockIdx.y * 64, b = blockIdx.z;
  __shared__ u16 tile[32][68];
  const int t = threadIdx.x;
  #pragma unroll
  for (int i = 0; i < 2; i++) {
    int idx4 = (i*256 + t) * 4;
    int cr = idx4 >> 6, sr = idx4 & 63;
    int c = c0 + cr;
    float4 v = *(const float4*)&x[((size_t)b*C_N + c)*S_N + s0 + sr];
    int bg = b*G_N + (c >> 4);
    float mean = stats[bg*2], rstd = stats[bg*2+1];
    float w = nw[c]*rstd;
    float bb = nb[c] - mean*w;
    tile[cr][sr]   = f2bf(v.x*w + bb);
    tile[cr][sr+1] = f2bf(v.y*w + bb);
    tile[cr][sr+2] = f2bf(v.z*w + bb);
    tile[cr][sr+3] = f2bf(v.w*w + bb);
  }
  __syncthreads();
  #pragma unroll
  for (int i = 0; i < 2; i++) {
    int idx = i*256 + t;
    int sr = idx >> 3;
    int cr4 = (idx & 7) * 4;
    u16x4 v = { tile[cr4][sr], tile[cr4+1][sr], tile[cr4+2][sr], tile[cr4+3][sr] };
    *(u16x4*)&h_t[((size_t)b*S_N + s0 + sr)*C_N + c0 + cr4] = v;
  }
}

// ---------------- fp32 -> bf16 weight convert ----------------
__global__ __launch_bounds__(256) void cvt_bf16_k(const float* __restrict__ src,
                                                  u16* __restrict__ dst, int n4) {
  int i = blockIdx.x*256 + threadIdx.x;
  if (i < n4) {
    float4 v = ((const float4*)src)[i];
    u16x4 r = { f2bf(v.x), f2bf(v.y), f2bf(v.z), f2bf(v.w) };
    ((u16x4*)dst)[i] = r;
  }
}

// ---------------- GEMM-1: qkv = h_t @ qkv_w^T, scatter to Q/K/V packs ----------------
// M = s (1024), N = o (1536), K = c (512). A=h_t[b] [S][C], B^T = qkv_w [O][C].
__global__ __launch_bounds__(256) void gemm_qkv(const u16* __restrict__ h_t,
                                                const u16* __restrict__ wq,
                                                const float* __restrict__ bq,
                                                u16* __restrict__ Qp,
                                                u16* __restrict__ Kp,
                                                u16* __restrict__ Vp) {
  __shared__ u16 Ash[128*32];
  __shared__ u16 Bsh[128*32];
  const int n0 = blockIdx.x*128, m0 = blockIdx.y*128, b = blockIdx.z;
  const int tid = threadIdx.x, wid = tid >> 6, lane = tid & 63;
  const int wm = wid >> 1, wn = wid & 1;
  const u16* Ag = h_t + (size_t)b*S_N*C_N;
  const f32x4 vzero = {0.f,0.f,0.f,0.f};
  f32x4 acc[4][4];
  #pragma unroll
  for (int i=0;i<4;i++)
    #pragma unroll
    for (int j=0;j<4;j++) acc[i][j] = vzero;

  const int arow = lane >> 2, aslot = (lane & 3) * 8;
  for (int k0 = 0; k0 < C_N; k0 += 32) {
    __syncthreads();
    #pragma unroll
    for (int i = 0; i < 2; i++) {
      int r = wid*32 + i*16 + arow;
      gll16(Ag + (size_t)(m0+r)*C_N + k0 + aslot, &Ash[(wid*32+i*16)*32]);
      gll16(wq + (size_t)(n0+r)*C_N + k0 + aslot, &Bsh[(wid*32+i*16)*32]);
    }
    __syncthreads();
    bf16x8 aF[4], bF[4];
    #pragma unroll
    for (int mi=0;mi<4;mi++)
      aF[mi] = *(const bf16x8*)&Ash[(wm*64+mi*16+(lane&15))*32 + (lane>>4)*8];
    #pragma unroll
    for (int ni=0;ni<4;ni++)
      bF[ni] = *(const bf16x8*)&Bsh[(wn*64+ni*16+(lane&15))*32 + (lane>>4)*8];
    #pragma unroll
    for (int mi=0;mi<4;mi++)
      #pragma unroll
      for (int ni=0;ni<4;ni++)
        acc[mi][ni] = __builtin_amdgcn_mfma_f32_16x16x32_bf16(aF[mi], bF[ni], acc[mi][ni], 0, 0, 0);
  }

  #pragma unroll
  for (int mi=0;mi<4;mi++) {
    #pragma unroll
    for (int ni=0;ni<4;ni++) {
      int o = n0 + wn*64 + ni*16 + (lane & 15);
      float bias = bq[o];
      int sec = o >> 9;
      int oo  = o & 511;
      int hh  = oo >> 6, d = oo & 63;
      size_t bh = (size_t)(b*NH + hh);
      #pragma unroll
      for (int r=0;r<4;r++) {
        int s = m0 + wm*64 + mi*16 + (lane>>4)*4 + r;
        u16 bv = f2bf(acc[mi][ni][r] + bias);
        if (sec == 0)      Qp[(bh*S_N + s)*HD + d] = bv;
        else if (sec == 1) Kp[(bh*S_N + s)*HD + d] = bv;
        else               Vp[(bh*HD + d)*S_N + s] = bv;
      }
    }
  }
}

// ---------------- flash attention: Q[s,d] @ K[t,d]^T -> softmax -> @ V[t,d] ----------------
__global__ __launch_bounds__(256) void attn_fwd(const u16* __restrict__ Qp,
                                                const u16* __restrict__ Kp,
                                                const u16* __restrict__ Vp,
                                                u16* __restrict__ at) {
  __shared__ u16 Kl[64*64];   // [t][d] rows 128B, slot XOR(t&7)
  __shared__ u16 Vl[64*64];   // [d][t] rows 128B, slot XOR(d&7)
  __shared__ u16 Pl[4*32*64]; // per-wave [s][t], slot XOR(s&7)
  const int q0 = blockIdx.x*128, hh = blockIdx.y, b = blockIdx.z;
  const int tid = threadIdx.x, wid = tid >> 6, lane = tid & 63;
  const size_t bh = (size_t)(b*NH + hh);
  const u16* Qb = Qp + bh*(S_N*HD);
  const u16* Kb = Kp + bh*(S_N*HD);
  const u16* Vb = Vp + bh*(HD*S_N);
  u16* pl = &Pl[wid*2048];
  const int sbase = q0 + wid*32;

  bf16x8 qf[2][2];
  #pragma unroll
  for (int mi=0;mi<2;mi++)
    #pragma unroll
    for (int kf=0;kf<2;kf++)
      qf[mi][kf] = *(const bf16x8*)&Qb[(size_t)(sbase + mi*16 + (lane&15))*HD + kf*32 + (lane>>4)*8];

  const f32x4 vzero = {0.f,0.f,0.f,0.f};
  f32x4 oacc[2][4];
  float m_run[2][4], l_run[2][4];
  #pragma unroll
  for (int mi=0;mi<2;mi++) {
    #pragma unroll
    for (int di=0;di<4;di++) oacc[mi][di] = vzero;
    #pragma unroll
    for (int r=0;r<4;r++) { m_run[mi][r] = -1e30f; l_run[mi][r] = 0.f; }
  }
  const float SC2 = 0.18033688011112042f;  // (1/sqrt(64)) * log2(e)

  for (int t0 = 0; t0 < S_N; t0 += 64) {
    __syncthreads();
    #pragma unroll
    for (int i = 0; i < 2; i++) {
      int rr = wid*16 + i*8 + (lane >> 3);
      int cs = (lane & 7) ^ (rr & 7);
      gll16(Kb + (size_t)(t0+rr)*HD + cs*8, &Kl[(wid*16+i*8)*64]);
      gll16(Vb + (size_t)rr*S_N + t0 + cs*8, &Vl[(wid*16+i*8)*64]);
    }
    __syncthreads();

    f32x4 st[2][4];
    #pragma unroll
    for (int mi=0;mi<2;mi++)
      #pragma unroll
      for (int ti=0;ti<4;ti++) st[mi][ti] = vzero;

    #pragma unroll
    for (int kf=0;kf<2;kf++) {
      #pragma unroll
      for (int ti=0;ti<4;ti++) {
        int trow = ti*16 + (lane & 15);
        int slot = (kf*4 + (lane>>4)) ^ (trow & 7);
        bf16x8 kF = *(const bf16x8*)&Kl[trow*64 + slot*8];
        #pragma unroll
        for (int mi=0;mi<2;mi++)
          st[mi][ti] = __builtin_amdgcn_mfma_f32_16x16x32_bf16(qf[mi][kf], kF, st[mi][ti], 0, 0, 0);
      }
    }

    // online softmax (scale folded into exp2 argument)
    #pragma unroll
    for (int mi=0;mi<2;mi++) {
      #pragma unroll
      for (int r=0;r<4;r++) {
        float v = fmaxf(fmaxf(st[mi][0][r], st[mi][1][r]), fmaxf(st[mi][2][r], st[mi][3][r]));
        v = fmaxf(v, __shfl_xor(v, 1));
        v = fmaxf(v, __shfl_xor(v, 2));
        v = fmaxf(v, __shfl_xor(v, 4));
        v = fmaxf(v, __shfl_xor(v, 8));
        float mnew  = fmaxf(m_run[mi][r], v);
        float alpha = exp2f((m_run[mi][r] - mnew) * SC2);
        m_run[mi][r] = mnew;
        float rs = 0.f;
        #pragma unroll
        for (int ti=0;ti<4;ti++) {
          float p = exp2f((st[mi][ti][r] - mnew) * SC2);
          st[mi][ti][r] = p;
          rs += p;
        }
        rs += __shfl_xor(rs, 1);
        rs += __shfl_xor(rs, 2);
        rs += __shfl_xor(rs, 4);
        rs += __shfl_xor(rs, 8);
        l_run[mi][r] = l_run[mi][r]*alpha + rs;
        #pragma unroll
        for (int di=0;di<4;di++) oacc[mi][di][r] *= alpha;
      }
    }

    // P -> wave-private LDS (swizzled), then PV
    #pragma unroll
    for (int mi=0;mi<2;mi++)
      #pragma unroll
      for (int ti=0;ti<4;ti++)
        #pragma unroll
        for (int r=0;r<4;r++) {
          int srow = mi*16 + (lane>>4)*4 + r;
          int t    = ti*16 + (lane & 15);
          int phys = (t>>3) ^ (srow & 7);
          pl[srow*64 + phys*8 + (t & 7)] = f2bf(st[mi][ti][r]);
        }

    #pragma unroll
    for (int kf2=0;kf2<2;kf2++) {
      bf16x8 pa[2];
      #pragma unroll
      for (int mi=0;mi<2;mi++) {
        int srow = mi*16 + (lane & 15);
        int slot = (kf2*4 + (lane>>4)) ^ (srow & 7);
        pa[mi] = *(const bf16x8*)&pl[srow*64 + slot*8];
      }
      #pragma unroll
      for (int di=0;di<4;di++) {
        int drow = di*16 + (lane & 15);
        int slot = (kf2*4 + (lane>>4)) ^ (drow & 7);
        bf16x8 vF = *(const bf16x8*)&Vl[drow*64 + slot*8];
        #pragma unroll
        for (int mi=0;mi<2;mi++)
          oacc[mi][di] = __builtin_amdgcn_mfma_f32_16x16x32_bf16(pa[mi], vF, oacc[mi][di], 0, 0, 0);
      }
    }
  }

  // epilogue: divide by l, write attn_t[b][s][c]
  #pragma unroll
  for (int mi=0;mi<2;mi++) {
    #pragma unroll
    for (int r=0;r<4;r++) {
      float inv = 1.0f / l_run[mi][r];
      int s = sbase + mi*16 + (lane>>4)*4 + r;
      #pragma unroll
      for (int di=0;di<4;di++)
        at[((size_t)b*S_N + s)*C_N + hh*HD + di*16 + (lane & 15)] = f2bf(oacc[mi][di][r] * inv);
    }
  }
}

// ---------------- GEMM-2: out = proj_w @ attn + bias + x ----------------
// M = o (512), N = s (1024), K = c (512). A = proj_w [O][C], B^T = attn_t[b] [S][C].
__global__ __launch_bounds__(256) void gemm_proj(const u16* __restrict__ pwb,
                                                 const u16* __restrict__ at,
                                                 const float* __restrict__ bp,
                                                 const float* __restrict__ x,
                                                 float* __restrict__ out) {
  __shared__ u16 Ash[128*32];
  __shared__ u16 Bsh[128*32];
  const int n0 = blockIdx.x*128, m0 = blockIdx.y*128, b = blockIdx.z;
  const int tid = threadIdx.x, wid = tid >> 6, lane = tid & 63;
  const int wm = wid >> 1, wn = wid & 1;
  const u16* Bg = at + (size_t)b*S_N*C_N;
  const f32x4 vzero = {0.f,0.f,0.f,0.f};
  f32x4 acc[4][4];
  #pragma unroll
  for (int i=0;i<4;i++)
    #pragma unroll
    for (int j=0;j<4;j++) acc[i][j] = vzero;

  const int arow = lane >> 2, aslot = (lane & 3) * 8;
  for (int k0 = 0; k0 < C_N; k0 += 32) {
    __syncthreads();
    #pragma unroll
    for (int i = 0; i < 2; i++) {
      int r = wid*32 + i*16 + arow;
      gll16(pwb + (size_t)(m0+r)*C_N + k0 + aslot, &Ash[(wid*32+i*16)*32]);
      gll16(Bg  + (size_t)(n0+r)*C_N + k0 + aslot, &Bsh[(wid*32+i*16)*32]);
    }
    __syncthreads();
    bf16x8 aF[4], bF[4];
    #pragma unroll
    for (int mi=0;mi<4;mi++)
      aF[mi] = *(const bf16x8*)&Ash[(wm*64+mi*16+(lane&15))*32 + (lane>>4)*8];
    #pragma unroll
    for (int ni=0;ni<4;ni++)
      bF[ni] = *(const bf16x8*)&Bsh[(wn*64+ni*16+(lane&15))*32 + (lane>>4)*8];
    #pragma unroll
    for (int mi=0;mi<4;mi++)
      #pragma unroll
      for (int ni=0;ni<4;ni++)
        acc[mi][ni] = __builtin_amdgcn_mfma_f32_16x16x32_bf16(aF[mi], bF[ni], acc[mi][ni], 0, 0, 0);
  }

  #pragma unroll
  for (int mi=0;mi<4;mi++) {
    #pragma unroll
    for (int ni=0;ni<4;ni++) {
      int ss = n0 + wn*64 + ni*16 + (lane & 15);
      #pragma unroll
      for (int r=0;r<4;r++) {
        int o = m0 + wm*64 + mi*16 + (lane>>4)*4 + r;
        size_t idx = ((size_t)b*C_N + o)*S_N + ss;
        out[idx] = acc[mi][ni][r] + bp[o] + x[idx];
      }
    }
  }
}

extern "C" void kernel_launch(void* const* d_in, const int* in_sizes, int n_in,
                              void* d_out, int out_size, void* d_ws, size_t ws_size,
                              hipStream_t stream) {
  const float* x     = (const float*)d_in[0];
  const float* nw    = (const float*)d_in[1];
  const float* nb    = (const float*)d_in[2];
  const float* qkvw  = (const float*)d_in[3];
  const float* qkvb  = (const float*)d_in[4];
  const float* projw = (const float*)d_in[5];
  const float* projb = (const float*)d_in[6];
  float* out = (float*)d_out;

  char* ws = (char*)d_ws;
  float* stats = (float*)ws;                              //   4 KB
  u16* h_t = (u16*)(ws + 4096);                           //  16 MB  [B][S][C]
  u16* qw  = (u16*)(ws + 4096 + 16777216);                // 1.5 MB  [1536][512]
  u16* pw  = (u16*)((char*)qw + 1572864);                 // 0.5 MB  [512][512]
  u16* Qp  = (u16*)((char*)pw + 524288);                  //  16 MB  [B][NH][S][HD]
  u16* Kp  = (u16*)((char*)Qp + 16777216);                //  16 MB  [B][NH][S][HD]
  u16* Vp  = (u16*)((char*)Kp + 16777216);                //  16 MB  [B][NH][HD][S]
  u16* at  = (u16*)((char*)Vp + 16777216);                //  16 MB  [B][S][C]

  gn_stats  <<<512, 256, 0, stream>>>(x, stats);
  gn_apply_t<<<dim3(16,16,16), 256, 0, stream>>>(x, stats, nw, nb, h_t);
  cvt_bf16_k<<<768, 256, 0, stream>>>(qkvw, qw, 196608);
  cvt_bf16_k<<<256, 256, 0, stream>>>(projw, pw, 65536);
  gemm_qkv  <<<dim3(12,8,16), 256, 0, stream>>>(h_t, qw, qkvb, Qp, Kp, Vp);
  attn_fwd  <<<dim3(8,8,16), 256, 0, stream>>>(Qp, Kp, Vp, at);
  gemm_proj <<<dim3(8,4,16), 256, 0, stream>>>(pw, at, projb, x, out);
}